// Round 2
// baseline (3520.165 us; speedup 1.0000x reference)
//
#include <hip/hip_runtime.h>

// PlayerPerformanceGNN: 2-layer GCN (32->16->8) + mean-pool + linear (8->5)
// N=1M, E=16M, G=10k.
// R2: bucket decomposition (dst>>BB), LDS accumulation, packed (dstLocal<<20)|src.
// R3: k_conv was latency-bound (VALUBusy 4.9%, HBM 20%, occ 41%).
//   - NPB 1024->512: conv1 acc 64KB->32KB -> 4 blocks/CU (occupancy cap 100%)
//   - hp = dis * (X@W) premultiply in the matmuls: removes the per-edge dis[s]
//     random 4B gather (di^2*h_i == di*hp_i, so epilogue = relu(di*(acc)+b)
//     with acc seeded by hp_i)
//   - edge loop unrolled 4x (more outstanding gathers per wave)
//   - __builtin_nontemporal on all pure streams (packed, dst/src, x, O-out) to
//     keep the 64MB hp gather target resident in L3
//   - MAXB 1024->2048, CHUNK 12288->8192 (binscatter LDS fits in 57KB)
// R3 fix: nontemporal builtins need clang ext_vector_type, not HIP float4.
// R1 lesson: scattered 4B global stores/atomics over 64MB targets = disaster;
// all scattered accumulation stays in LDS.

namespace {

constexpr int F_IN = 32, F_H1 = 16, F_H2 = 8, N_CLS = 5;
constexpr int BB = 9, NPB = 1 << BB;    // nodes per bucket = 512
constexpr int MAXB = 2048;              // bucket-table size (N <= 2^20)
constexpr int CHUNK = 8192;             // edges per binscatter block (32KB stage)

typedef float v4f __attribute__((ext_vector_type(4)));

// ---------------- dense matmuls (optionally premultiplied by dis) ----------------

__global__ void k_mm1(const float* __restrict__ x, const float* __restrict__ W,
                      const float* __restrict__ dis, float* __restrict__ hp, int N) {
  __shared__ float w[F_IN * F_H1];
  for (int k = threadIdx.x; k < F_IN * F_H1; k += blockDim.x) w[k] = W[k];
  __syncthreads();
  int i = blockIdx.x * blockDim.x + threadIdx.x;
  if (i >= N) return;
  const v4f* xr = reinterpret_cast<const v4f*>(x + (size_t)i * F_IN);
  float acc[F_H1];
#pragma unroll
  for (int f = 0; f < F_H1; ++f) acc[f] = 0.f;
#pragma unroll
  for (int k4 = 0; k4 < F_IN / 4; ++k4) {
    v4f v = __builtin_nontemporal_load(&xr[k4]);
    float vv[4] = {v.x, v.y, v.z, v.w};
#pragma unroll
    for (int j = 0; j < 4; ++j) {
      const float* wr = &w[(k4 * 4 + j) * F_H1];
#pragma unroll
      for (int f = 0; f < F_H1; ++f) acc[f] = fmaf(vv[j], wr[f], acc[f]);
    }
  }
  float di = dis ? dis[i] : 1.f;
  v4f* hr = reinterpret_cast<v4f*>(hp + (size_t)i * F_H1);
#pragma unroll
  for (int q = 0; q < F_H1 / 4; ++q) {
    v4f r;
    r.x = di * acc[q * 4];
    r.y = di * acc[q * 4 + 1];
    r.z = di * acc[q * 4 + 2];
    r.w = di * acc[q * 4 + 3];
    hr[q] = r;
  }
}

__global__ void k_mm2(const float* __restrict__ in, const float* __restrict__ W,
                      const float* __restrict__ dis, float* __restrict__ hp, int N) {
  __shared__ float w[F_H1 * F_H2];
  for (int k = threadIdx.x; k < F_H1 * F_H2; k += blockDim.x) w[k] = W[k];
  __syncthreads();
  int i = blockIdx.x * blockDim.x + threadIdx.x;
  if (i >= N) return;
  const v4f* xr = reinterpret_cast<const v4f*>(in + (size_t)i * F_H1);
  float acc[F_H2];
#pragma unroll
  for (int f = 0; f < F_H2; ++f) acc[f] = 0.f;
#pragma unroll
  for (int k4 = 0; k4 < F_H1 / 4; ++k4) {
    v4f v = __builtin_nontemporal_load(&xr[k4]);
    float vv[4] = {v.x, v.y, v.z, v.w};
#pragma unroll
    for (int j = 0; j < 4; ++j) {
      const float* wr = &w[(k4 * 4 + j) * F_H2];
#pragma unroll
      for (int f = 0; f < F_H2; ++f) acc[f] = fmaf(vv[j], wr[f], acc[f]);
    }
  }
  float di = dis ? dis[i] : 1.f;
  v4f* hr = reinterpret_cast<v4f*>(hp + (size_t)i * F_H2);
#pragma unroll
  for (int q = 0; q < F_H2 / 4; ++q) {
    v4f r;
    r.x = di * acc[q * 4];
    r.y = di * acc[q * 4 + 1];
    r.z = di * acc[q * 4 + 2];
    r.w = di * acc[q * 4 + 3];
    hr[q] = r;
  }
}

__global__ void k_final(const float* __restrict__ pooled, const float* __restrict__ cnts,
                        const float* __restrict__ Wl, const float* __restrict__ bl,
                        float* __restrict__ out, int total) {
  int gid = blockIdx.x * blockDim.x + threadIdx.x;
  if (gid >= total) return;
  int g = gid / N_CLS, c = gid % N_CLS;
  float s = 0.f;
#pragma unroll
  for (int f = 0; f < F_H2; ++f) s += pooled[g * F_H2 + f] * Wl[f * N_CLS + c];
  out[gid] = s / fmaxf(cnts[g], 1.f) + bl[c];
}

// ---------------- bucket build ----------------

__global__ void k_hist(const int* __restrict__ dst, int* __restrict__ bcnt,
                       int E, int nbuck) {
  __shared__ int h[MAXB];
  for (int i = threadIdx.x; i < MAXB; i += blockDim.x) h[i] = 0;
  __syncthreads();
  for (int e = blockIdx.x * blockDim.x + threadIdx.x; e < E;
       e += gridDim.x * blockDim.x)
    atomicAdd(&h[__builtin_nontemporal_load(&dst[e]) >> BB], 1);
  __syncthreads();
  for (int i = threadIdx.x; i < nbuck; i += blockDim.x)
    if (h[i]) atomicAdd(&bcnt[i], h[i]);
}

// single block, 1024 threads, 2 entries/thread: exclusive scan bcnt -> bbase (+bcur)
__global__ void k_bscan(const int* __restrict__ bcnt, int* __restrict__ bbase,
                        int* __restrict__ bcur, int nbuck, int E) {
  __shared__ int stmp[1024];
  int t = threadIdx.x;
  int i0 = t * 2;
  int v0 = (i0 < nbuck) ? bcnt[i0] : 0;
  int v1 = (i0 + 1 < nbuck) ? bcnt[i0 + 1] : 0;
  int sum = v0 + v1;
  stmp[t] = sum;
  __syncthreads();
  for (int off = 1; off < 1024; off <<= 1) {
    int x = (t >= off) ? stmp[t - off] : 0;
    __syncthreads();
    stmp[t] += x;
    __syncthreads();
  }
  int run = stmp[t] - sum;
  if (i0 < nbuck) { bbase[i0] = run; bcur[i0] = run; }
  if (i0 + 1 < nbuck) { bbase[i0 + 1] = run + v0; bcur[i0 + 1] = run + v0; }
  if (t == 0) bbase[nbuck] = E;
}

// LDS-staged binned scatter: packed[pos] = (dstLocal<<20)|src, grouped by bucket
__global__ __launch_bounds__(256)
void k_binscatter(const int* __restrict__ dst, const int* __restrict__ src,
                  int* __restrict__ bcur, int* __restrict__ packed, int E) {
  __shared__ int hist[MAXB];       // chunk counts; rewritten as global base
  __shared__ int sbase[MAXB];      // exclusive scan of chunk counts
  __shared__ int lcur[MAXB];       // local cursor
  __shared__ int stg[CHUNK];       // staged packed edges, bucket order
  __shared__ int stmp[256];
  int t = threadIdx.x;
  int c0 = blockIdx.x * CHUNK;
  int n = min(CHUNK, E - c0);
  for (int i = t; i < MAXB; i += 256) hist[i] = 0;
  __syncthreads();
  for (int j = t; j < n; j += 256)
    atomicAdd(&hist[__builtin_nontemporal_load(&dst[c0 + j]) >> BB], 1);
  __syncthreads();
  // exclusive scan (8 entries/thread)
  int v[8], sum = 0;
  int b8 = t * 8;
#pragma unroll
  for (int k = 0; k < 8; ++k) { v[k] = hist[b8 + k]; sum += v[k]; }
  stmp[t] = sum;
  __syncthreads();
  for (int off = 1; off < 256; off <<= 1) {
    int x = (t >= off) ? stmp[t - off] : 0;
    __syncthreads();
    stmp[t] += x;
    __syncthreads();
  }
  int run = stmp[t] - sum;
#pragma unroll
  for (int k = 0; k < 8; ++k) { sbase[b8 + k] = run; lcur[b8 + k] = run; run += v[k]; }
  __syncthreads();
  // reserve one contiguous global range per (block,bucket); hist becomes gbase
  for (int i = t; i < MAXB; i += 256) {
    int c = hist[i];
    if (c) hist[i] = atomicAdd(&bcur[i], c);
  }
  __syncthreads();
  // stage chunk edges in bucket order
  for (int j = t; j < n; j += 256) {
    int d = __builtin_nontemporal_load(&dst[c0 + j]);
    int s = __builtin_nontemporal_load(&src[c0 + j]);
    int b = d >> BB;
    int p = atomicAdd(&lcur[b], 1);
    stg[p] = ((d & (NPB - 1)) << 20) | s;
  }
  __syncthreads();
  // write out: consecutive j in same bucket -> coalesced runs
  for (int j = t; j < n; j += 256) {
    int lo = 0, hi = MAXB - 1;
    while (lo < hi) {  // max b with sbase[b] <= j
      int mid = (lo + hi + 1) >> 1;
      if (sbase[mid] <= j) lo = mid; else hi = mid - 1;
    }
    packed[hist[lo] + (j - sbase[lo])] = stg[j];
  }
}

// per-bucket degree count -> dis = rsqrt(deg+1)
__global__ void k_dis_b(const int* __restrict__ bbase, const int* __restrict__ packed,
                        float* __restrict__ dis, int N) {
  __shared__ int cnt[NPB];
  int t = threadIdx.x;
  for (int i = t; i < NPB; i += blockDim.x) cnt[i] = 0;
  __syncthreads();
  int b = blockIdx.x;
  int beg = bbase[b], end = bbase[b + 1];
  for (int e = beg + t; e < end; e += blockDim.x)
    atomicAdd(&cnt[__builtin_nontemporal_load(&packed[e]) >> 20], 1);
  __syncthreads();
  int node0 = b << BB;
  for (int i = t; i < NPB; i += blockDim.x) {
    int node = node0 + i;
    if (node < N) dis[node] = rsqrtf((float)cnt[i] + 1.0f);
  }
}

// ---------------- bucketed conv (LDS accumulate) ----------------
// hp = dis .* (X W);  out_i = relu( dis_i * (sum_{j->i} hp_j + hp_i) + b )
// (self loop: di^2 * h_i == di * hp_i, so seed acc with hp_i)

template <int F>
__global__ __launch_bounds__(512, 8)
void k_conv(const int* __restrict__ bbase, const int* __restrict__ packed,
            const float* __restrict__ dis, const float* __restrict__ hp,
            const float* __restrict__ bias, float* __restrict__ out, int N) {
  __shared__ float acc[NPB * F];  // F=16: 32KB -> 4 blocks/CU
  int t = threadIdx.x;
  int b = blockIdx.x;
  int node0 = b << BB;
  // seed acc with self contribution hp_i (coalesced v4f)
  for (int i4 = t; i4 < NPB * F / 4; i4 += 512) {
    int idx = i4 * 4;
    int node = node0 + idx / F;
    v4f v = {0.f, 0.f, 0.f, 0.f};
    if (node < N) v = *reinterpret_cast<const v4f*>(hp + (size_t)node0 * F + idx);
    *reinterpret_cast<v4f*>(&acc[idx]) = v;
  }
  __syncthreads();
  int beg = bbase[b], end = bbase[b + 1];
  const int EPI = 512 / F;
  int f = t % F, eg = t / F;
  for (int e = beg + eg; e < end; e += 4 * EPI) {
    int pe[4]; float hv[4]; int dl[4]; bool ok[4];
#pragma unroll
    for (int u = 0; u < 4; ++u) {
      int ee = e + u * EPI;
      ok[u] = ee < end;
      pe[u] = ok[u] ? __builtin_nontemporal_load(&packed[ee]) : 0;
    }
#pragma unroll
    for (int u = 0; u < 4; ++u) {
      int s = pe[u] & 0xFFFFF;
      dl[u] = pe[u] >> 20;
      hv[u] = ok[u] ? hp[(size_t)s * F + f] : 0.f;
    }
#pragma unroll
    for (int u = 0; u < 4; ++u)
      if (ok[u]) atomicAdd(&acc[dl[u] * F + f], hv[u]);
  }
  __syncthreads();
  // epilogue: out = relu(dis_i * acc + b), streamed (nt) v4f
  for (int i4 = t; i4 < NPB * F / 4; i4 += 512) {
    int idx = i4 * 4;
    int node = node0 + idx / F;
    if (node >= N) continue;
    int ff = idx % F;
    float di = dis[node];
    v4f a = *reinterpret_cast<const v4f*>(&acc[idx]);
    v4f r;
    r.x = fmaxf(fmaf(di, a.x, bias[ff + 0]), 0.f);
    r.y = fmaxf(fmaf(di, a.y, bias[ff + 1]), 0.f);
    r.z = fmaxf(fmaf(di, a.z, bias[ff + 2]), 0.f);
    r.w = fmaxf(fmaf(di, a.w, bias[ff + 3]), 0.f);
    __builtin_nontemporal_store(r, reinterpret_cast<v4f*>(out + (size_t)node0 * F + idx));
  }
}

// conv2 + mean-pool epilogue (no h_out write)
__global__ __launch_bounds__(512, 8)
void k_conv_pool(const int* __restrict__ bbase, const int* __restrict__ packed,
                 const float* __restrict__ dis, const float* __restrict__ hp,
                 const float* __restrict__ bias, const int* __restrict__ batch,
                 float* __restrict__ pooled, float* __restrict__ cnts, int N) {
  constexpr int F = F_H2;
  __shared__ float acc[NPB * F];  // 16KB
  int t = threadIdx.x;
  int b = blockIdx.x;
  int node0 = b << BB;
  for (int i4 = t; i4 < NPB * F / 4; i4 += 512) {
    int idx = i4 * 4;
    int node = node0 + idx / F;
    v4f v = {0.f, 0.f, 0.f, 0.f};
    if (node < N) v = *reinterpret_cast<const v4f*>(hp + (size_t)node0 * F + idx);
    *reinterpret_cast<v4f*>(&acc[idx]) = v;
  }
  __syncthreads();
  int beg = bbase[b], end = bbase[b + 1];
  const int EPI = 512 / F;
  int f = t % F, eg = t / F;
  for (int e = beg + eg; e < end; e += 4 * EPI) {
    int pe[4]; float hv[4]; int dl[4]; bool ok[4];
#pragma unroll
    for (int u = 0; u < 4; ++u) {
      int ee = e + u * EPI;
      ok[u] = ee < end;
      pe[u] = ok[u] ? __builtin_nontemporal_load(&packed[ee]) : 0;
    }
#pragma unroll
    for (int u = 0; u < 4; ++u) {
      int s = pe[u] & 0xFFFFF;
      dl[u] = pe[u] >> 20;
      hv[u] = ok[u] ? hp[(size_t)s * F + f] : 0.f;
    }
#pragma unroll
    for (int u = 0; u < 4; ++u)
      if (ok[u]) atomicAdd(&acc[dl[u] * F + f], hv[u]);
  }
  __syncthreads();
  for (int i = t; i < NPB * F; i += 512) {
    int node = node0 + i / F;
    if (node >= N) continue;
    int ff = i % F;
    float di = dis[node];
    float v = fmaxf(fmaf(di, acc[i], bias[ff]), 0.f);
    int g = batch[node];
    atomicAdd(&pooled[g * F_H2 + ff], v);
    if (ff == 0) atomicAdd(&cnts[g], 1.0f);
  }
}

// ---------------- fallback (round-0 scatter atomics) ----------------

__global__ void k_deg(const int* __restrict__ dst, float* __restrict__ deg, int E) {
  int e = blockIdx.x * blockDim.x + threadIdx.x;
  if (e < E) atomicAdd(&deg[dst[e]], 1.0f);
}
__global__ void k_dis(float* __restrict__ d, int N) {
  int i = blockIdx.x * blockDim.x + threadIdx.x;
  if (i < N) d[i] = rsqrtf(d[i] + 1.0f);
}
template <int F>
__global__ void k_edge(const int* __restrict__ src, const int* __restrict__ dst,
                       const float* __restrict__ dis, const float* __restrict__ h,
                       float* __restrict__ agg, int total) {
  int gid = blockIdx.x * blockDim.x + threadIdx.x;
  if (gid >= total) return;
  int e = gid / F, f = gid % F;
  int s = src[e], d = dst[e];
  atomicAdd(&agg[d * F + f], h[s * F + f] * dis[s] * dis[d]);
}
template <int F>
__global__ void k_combine(const float* __restrict__ h, const float* __restrict__ dis,
                          const float* __restrict__ b, float* __restrict__ agg, int total) {
  int gid = blockIdx.x * blockDim.x + threadIdx.x;
  if (gid >= total) return;
  int i = gid / F, f = gid % F;
  float di = dis[i];
  agg[gid] = fmaxf(agg[gid] + h[gid] * di * di + b[f], 0.f);
}
__global__ void k_combine_pool_fb(const float* __restrict__ h2, const float* __restrict__ agg2,
                                  const float* __restrict__ dis, const float* __restrict__ b,
                                  const int* __restrict__ batch, float* __restrict__ pooled,
                                  float* __restrict__ cnts, int total) {
  int gid = blockIdx.x * blockDim.x + threadIdx.x;
  if (gid >= total) return;
  int i = gid >> 3, f = gid & 7;
  float di = dis[i];
  float v = fmaxf(agg2[gid] + h2[gid] * di * di + b[f], 0.f);
  int g = batch[i];
  atomicAdd(&pooled[g * F_H2 + f], v);
  if (f == 0) atomicAdd(&cnts[g], 1.0f);
}

}  // namespace

extern "C" void kernel_launch(void* const* d_in, const int* in_sizes, int n_in,
                              void* d_out, int out_size, void* d_ws, size_t ws_size,
                              hipStream_t stream) {
  const float* x   = (const float*)d_in[0];
  const int* ei    = (const int*)d_in[1];
  const int* batch = (const int*)d_in[2];
  const float* W1 = (const float*)d_in[4];
  const float* b1 = (const float*)d_in[5];
  const float* W2 = (const float*)d_in[6];
  const float* b2 = (const float*)d_in[7];
  const float* Wl = (const float*)d_in[8];
  const float* bl = (const float*)d_in[9];

  const int N = in_sizes[0] / F_IN;   // 1,000,000
  const int E = in_sizes[1] / 2;      // 16,000,000
  const int G = out_size / N_CLS;     // 10,000
  const int* src  = ei;
  const int* dstp = ei + E;

  const int BLK = 256;
  const int nbuck = (N + NPB - 1) >> BB;

  size_t need = (size_t)(3 * MAXB + 8) * 4   // bcnt, bbase, bcur
              + (size_t)E * 4                // packed
              + (size_t)N * 4                // dis
              + (size_t)N * F_H1 * 4         // H (hp1, later hp2)
              + (size_t)N * F_H1 * 4         // O (out1)
              + (size_t)G * (F_H2 + 1) * 4 + 1024;

  if (N <= (1 << 20) && nbuck <= MAXB && ws_size >= need) {
    char* p = (char*)d_ws;
    int*   bcnt   = (int*)p;    p += (size_t)MAXB * 4;
    int*   bbase  = (int*)p;    p += (size_t)(MAXB + 4) * 4;
    int*   bcur   = (int*)p;    p += (size_t)MAXB * 4;
    int*   packed = (int*)p;    p += (size_t)E * 4;
    float* dis    = (float*)p;  p += (size_t)N * 4;
    float* H      = (float*)p;  p += (size_t)N * F_H1 * 4;
    float* O      = (float*)p;  p += (size_t)N * F_H1 * 4;
    float* pooled = (float*)p;  p += (size_t)G * F_H2 * 4;
    float* cnts   = (float*)p;

    (void)hipMemsetAsync(bcnt, 0, (size_t)MAXB * 4, stream);
    (void)hipMemsetAsync(pooled, 0, ((size_t)G * F_H2 + G) * 4, stream);

    // bucket build (dis before mm1 so the matmul can premultiply)
    k_hist<<<2048, BLK, 0, stream>>>(dstp, bcnt, E, nbuck);
    k_bscan<<<1, 1024, 0, stream>>>(bcnt, bbase, bcur, nbuck, E);
    k_binscatter<<<(E + CHUNK - 1) / CHUNK, BLK, 0, stream>>>(dstp, src, bcur, packed, E);
    k_dis_b<<<nbuck, BLK, 0, stream>>>(bbase, packed, dis, N);

    // conv1: hp1 = dis .* (x @ W1)
    k_mm1<<<(N + BLK - 1) / BLK, BLK, 0, stream>>>(x, W1, dis, H, N);
    k_conv<F_H1><<<nbuck, 512, 0, stream>>>(bbase, packed, dis, H, b1, O, N);
    // conv2: hp2 = dis .* (O @ W2)  (reuses H)
    k_mm2<<<(N + BLK - 1) / BLK, BLK, 0, stream>>>(O, W2, dis, H, N);
    k_conv_pool<<<nbuck, 512, 0, stream>>>(bbase, packed, dis, H, b2, batch,
                                           pooled, cnts, N);

    k_final<<<(G * N_CLS + BLK - 1) / BLK, BLK, 0, stream>>>(
        pooled, cnts, Wl, bl, (float*)d_out, G * N_CLS);
    return;
  }

  // ---------- fallback: round-0 scatter-atomic path ----------
  float* ws = (float*)d_ws;
  float* dis    = ws;
  float* A      = ws + N;
  float* B      = A + (size_t)N * F_H1;
  float* h2     = A;
  float* agg2   = A + (size_t)N * F_H2;
  float* pooled = B + (size_t)N * F_H1;
  float* cnts   = pooled + (size_t)G * F_H2;

  (void)hipMemsetAsync(dis, 0, (size_t)N * sizeof(float), stream);
  (void)hipMemsetAsync(B, 0, (size_t)N * F_H1 * sizeof(float), stream);
  (void)hipMemsetAsync(pooled, 0, ((size_t)G * F_H2 + G) * sizeof(float), stream);

  k_deg<<<(E + BLK - 1) / BLK, BLK, 0, stream>>>(dstp, dis, E);
  k_dis<<<(N + BLK - 1) / BLK, BLK, 0, stream>>>(dis, N);
  k_mm1<<<(N + BLK - 1) / BLK, BLK, 0, stream>>>(x, W1, nullptr, A, N);
  k_edge<F_H1><<<(E * F_H1 + BLK - 1) / BLK, BLK, 0, stream>>>(src, dstp, dis, A, B, E * F_H1);
  k_combine<F_H1><<<(N * F_H1 + BLK - 1) / BLK, BLK, 0, stream>>>(A, dis, b1, B, N * F_H1);
  (void)hipMemsetAsync(agg2, 0, (size_t)N * F_H2 * sizeof(float), stream);
  k_mm2<<<(N + BLK - 1) / BLK, BLK, 0, stream>>>(B, W2, nullptr, h2, N);
  k_edge<F_H2><<<(E * F_H2 + BLK - 1) / BLK, BLK, 0, stream>>>(src, dstp, dis, h2, agg2, E * F_H2);
  k_combine_pool_fb<<<(N * F_H2 + BLK - 1) / BLK, BLK, 0, stream>>>(
      h2, agg2, dis, b2, batch, pooled, cnts, N * F_H2);
  k_final<<<(G * N_CLS + BLK - 1) / BLK, BLK, 0, stream>>>(
      pooled, cnts, Wl, bl, (float*)d_out, G * N_CLS);
}